// Round 1
// baseline (359.834 us; speedup 1.0000x reference)
//
#include <hip/hip_runtime.h>
#include <math.h>

#define NT 2560
#define D 32
#define NBATCH 4
#define TILE_N 32
#define TILE_M 64
#define SELF_EPS 0.5f
#define NTHREADS 256

__device__ __forceinline__ float fast_rcp(float x) {
#if __has_builtin(__builtin_amdgcn_rcpf)
    return __builtin_amdgcn_rcpf(x);
#else
    return 1.0f / x;
#endif
}

// tanh(relu(x)) = 1 - 2/(exp(2x)+1) for x>=0
__device__ __forceinline__ float tanh_relu(float x) {
    x = fmaxf(x, 0.0f);
    float e = __expf(x + x);
    return 1.0f - 2.0f * fast_rcp(e + 1.0f);
}

__global__ __launch_bounds__(NTHREADS, 2)
void gsage_layer(const float* __restrict__ X,    // [B][NT][D] (adjacency source)
                 const float* __restrict__ Hin,  // [B][NT][D]
                 const float* __restrict__ Ws,   // [D][D] this layer
                 const float* __restrict__ Wn,   // [D][D] this layer
                 const float* __restrict__ bias, // [D]   this layer
                 float* __restrict__ Hout)       // [B][NT][D]
{
    // row strides padded to 36 floats (144B: 16B-aligned float4 rows, worst
    // phase-1 bank aliasing is 2-way which is free on gfx950)
    __shared__ __align__(16) float sXn[TILE_N][36];
    __shared__ __align__(16) float sXm[TILE_M][36];
    __shared__ __align__(16) float sHm[TILE_M][36];
    __shared__ __align__(16) float sS [TILE_N][TILE_M + 4];
    __shared__ __align__(16) float sAgg[TILE_N][36];
    __shared__ __align__(16) float sWs[D][33];
    __shared__ __align__(16) float sWn[D][33];

    const int t  = threadIdx.x;
    const int b  = blockIdx.y;
    const int n0 = blockIdx.x * TILE_N;

    const float* __restrict__ Xb = X   + (size_t)b * NT * D;
    const float* __restrict__ Hb = Hin + (size_t)b * NT * D;

    // ---- stage Xn tile (32x32) and the layer weights ----
    {
        const int row = t >> 3, c4 = (t & 7) * 4;
        *(float4*)&sXn[row][c4] = *(const float4*)(Xb + (size_t)(n0 + row) * D + c4);
        const float4 w0 = *(const float4*)(Ws + row * D + c4);
        const float4 w1 = *(const float4*)(Wn + row * D + c4);
        sWs[row][c4+0] = w0.x; sWs[row][c4+1] = w0.y; sWs[row][c4+2] = w0.z; sWs[row][c4+3] = w0.w;
        sWn[row][c4+0] = w1.x; sWn[row][c4+1] = w1.y; sWn[row][c4+2] = w1.z; sWn[row][c4+3] = w1.w;
    }

    const int tn = t & 15;        // phase-1: n in {tn, tn+16}
    const int tm = t >> 4;        // phase-1: m in {4tm..4tm+3}
    const int pn = t >> 3;        // phase-2/epilogue: n row (0..31)
    const int dq = (t & 7) * 4;   // phase-2/epilogue: d base

    float4 acc = make_float4(0.f, 0.f, 0.f, 0.f);

    for (int mt = 0; mt < NT / TILE_M; ++mt) {
        const int m0 = mt * TILE_M;
        __syncthreads();   // previous phase-2 done with sS/sHm

        // ---- stage Xm, Hm tiles (64x32 each): 2 float4 per thread per array
        #pragma unroll
        for (int i = 0; i < 2; ++i) {
            const int f = t + i * NTHREADS;
            const int row = f >> 3, c4 = (f & 7) * 4;
            *(float4*)&sXm[row][c4] = *(const float4*)(Xb + (size_t)(m0 + row) * D + c4);
            *(float4*)&sHm[row][c4] = *(const float4*)(Hb + (size_t)(m0 + row) * D + c4);
        }
        __syncthreads();

        // ---- phase 1: S[n][m] = tanh(relu(xn . xm)) (+ self loop) ----
        float s[2][4];
        #pragma unroll
        for (int i = 0; i < 2; ++i)
            #pragma unroll
            for (int j = 0; j < 4; ++j) s[i][j] = 0.f;

        #pragma unroll
        for (int k = 0; k < D; k += 4) {
            float4 a[2], bb[4];
            a[0] = *(const float4*)&sXn[tn     ][k];
            a[1] = *(const float4*)&sXn[tn + 16][k];
            #pragma unroll
            for (int j = 0; j < 4; ++j)
                bb[j] = *(const float4*)&sXm[4*tm + j][k];
            #pragma unroll
            for (int i = 0; i < 2; ++i)
                #pragma unroll
                for (int j = 0; j < 4; ++j)
                    s[i][j] += a[i].x*bb[j].x + a[i].y*bb[j].y
                             + a[i].z*bb[j].z + a[i].w*bb[j].w;
        }

        #pragma unroll
        for (int i = 0; i < 2; ++i)
            #pragma unroll
            for (int j = 0; j < 4; ++j) {
                float v = tanh_relu(s[i][j]);
                const int gn = n0 + tn + 16*i;
                const int gm = m0 + 4*tm + j;
                v += (gn == gm) ? SELF_EPS : 0.0f;
                sS[tn + 16*i][4*tm + j] = v;
            }
        __syncthreads();

        // ---- phase 2: acc[n][d] += sum_m S[n][m] * Hm[m][d] ----
        #pragma unroll
        for (int m = 0; m < TILE_M; m += 4) {
            const float4 sv = *(const float4*)&sS[pn][m];
            const float4 h0 = *(const float4*)&sHm[m+0][dq];
            const float4 h1 = *(const float4*)&sHm[m+1][dq];
            const float4 h2 = *(const float4*)&sHm[m+2][dq];
            const float4 h3 = *(const float4*)&sHm[m+3][dq];
            acc.x += sv.x*h0.x + sv.y*h1.x + sv.z*h2.x + sv.w*h3.x;
            acc.y += sv.x*h0.y + sv.y*h1.y + sv.z*h2.y + sv.w*h3.y;
            acc.z += sv.x*h0.z + sv.y*h1.z + sv.z*h2.z + sv.w*h3.z;
            acc.w += sv.x*h0.w + sv.y*h1.w + sv.z*h2.w + sv.w*h3.w;
        }
    }

    __syncthreads();   // all phase-2 reads of sHm done
    // stash agg; restage this block's Hin rows into sHm[0..31]
    sAgg[pn][dq+0] = acc.x; sAgg[pn][dq+1] = acc.y;
    sAgg[pn][dq+2] = acc.z; sAgg[pn][dq+3] = acc.w;
    {
        const int row = t >> 3, c4 = (t & 7) * 4;
        *(float4*)&sHm[row][c4] = *(const float4*)(Hb + (size_t)(n0 + row) * D + c4);
    }
    __syncthreads();

    // ---- epilogue: Hout[n][d] = elu(h[n]·Ws + agg[n]·Wn + b) ----
    float4 z;
    z.x = bias[dq+0]; z.y = bias[dq+1]; z.z = bias[dq+2]; z.w = bias[dq+3];
    #pragma unroll
    for (int k = 0; k < D; ++k) {
        const float hk = sHm[pn][k];
        const float ak = sAgg[pn][k];
        z.x += hk * sWs[k][dq+0] + ak * sWn[k][dq+0];
        z.y += hk * sWs[k][dq+1] + ak * sWn[k][dq+1];
        z.z += hk * sWs[k][dq+2] + ak * sWn[k][dq+2];
        z.w += hk * sWs[k][dq+3] + ak * sWn[k][dq+3];
    }
    z.x = z.x > 0.f ? z.x : __expf(z.x) - 1.f;
    z.y = z.y > 0.f ? z.y : __expf(z.y) - 1.f;
    z.z = z.z > 0.f ? z.z : __expf(z.z) - 1.f;
    z.w = z.w > 0.f ? z.w : __expf(z.w) - 1.f;
    *(float4*)(Hout + ((size_t)b * NT + n0 + pn) * D + dq) = z;
}

extern "C" void kernel_launch(void* const* d_in, const int* in_sizes, int n_in,
                              void* d_out, int out_size, void* d_ws, size_t ws_size,
                              hipStream_t stream) {
    const float* X  = (const float*)d_in[0];
    const float* Ws = (const float*)d_in[1];   // [2][32][32]
    const float* Wn = (const float*)d_in[2];   // [2][32][32]
    const float* bv = (const float*)d_in[3];   // [2][32]
    float* h1  = (float*)d_ws;                 // [B][NT][D] intermediate
    float* out = (float*)d_out;

    dim3 grid(NT / TILE_N, NBATCH);
    // layer 0: h_in = X
    gsage_layer<<<grid, NTHREADS, 0, stream>>>(X, X,  Ws,          Wn,          bv,      h1);
    // layer 1: h_in = h1
    gsage_layer<<<grid, NTHREADS, 0, stream>>>(X, h1, Ws + D * D,  Wn + D * D,  bv + D,  out);
}

// Round 2
// 102.636 us; speedup vs baseline: 3.5059x; 3.5059x over previous
//
#include <hip/hip_runtime.h>
#include <math.h>

#define NT 2560
#define DF 32
#define NB 4
#define SELF_EPS 0.5f
#define MS 8                 // m-split across blocks
#define MROWS (NT / MS)      // 320 m rows per block
#define MT 64                // m tile
#define MITERS (MROWS / MT)  // 5
#define TN 64                // n rows per block (4 waves x 16)

typedef __attribute__((ext_vector_type(8))) short bf16x8;
typedef __attribute__((ext_vector_type(4))) float f32x4;

__device__ __forceinline__ unsigned short f2bf(float f) {
    unsigned u = __builtin_bit_cast(unsigned, f);
    u += 0x7fffu + ((u >> 16) & 1u);   // RNE
    return (unsigned short)(u >> 16);
}

__device__ __forceinline__ float fast_rcp(float x) {
#if __has_builtin(__builtin_amdgcn_rcpf)
    return __builtin_amdgcn_rcpf(x);
#else
    return 1.0f / x;
#endif
}

// tanh(relu(x)) = 1 - 2/(exp(2x)+1) for x>=0
__device__ __forceinline__ float tanh_relu(float x) {
    x = fmaxf(x, 0.0f);
    float e = __expf(x + x);
    return 1.0f - 2.0f * fast_rcp(e + 1.0f);
}

// ---------------------------------------------------------------------------
// prep: blocks [0,640) zero agg1+agg2 (2.6 MB); blocks [640,960) convert
// X fp32 -> Xb bf16 row-major [B][NT][32] and XT bf16 transposed [B][32][NT].
// ---------------------------------------------------------------------------
__global__ __launch_bounds__(256, 4)
void prep(const float* __restrict__ X, float* __restrict__ aggz,
          unsigned short* __restrict__ Xb, unsigned short* __restrict__ XT)
{
    const int bid = blockIdx.x, t = threadIdx.x;
    if (bid < 640) {
        f32x4 z = {0.f, 0.f, 0.f, 0.f};
        ((f32x4*)aggz)[(size_t)bid * 256 + t] = z;
        return;
    }
    __shared__ float sT[32][33];
    const int tile = bid - 640;
    const int b = tile / 80, n0 = (tile % 80) * 32;
    const int row = t >> 3, c4 = (t & 7) * 4;
    const size_t rbase = ((size_t)(b * NT + n0 + row)) * DF + c4;
    const float4 v = *(const float4*)(X + rbase);
    // row-major bf16
    unsigned p0 = (unsigned)f2bf(v.x) | ((unsigned)f2bf(v.y) << 16);
    unsigned p1 = (unsigned)f2bf(v.z) | ((unsigned)f2bf(v.w) << 16);
    *(uint2*)(Xb + rbase) = make_uint2(p0, p1);
    sT[row][c4 + 0] = v.x; sT[row][c4 + 1] = v.y;
    sT[row][c4 + 2] = v.z; sT[row][c4 + 3] = v.w;
    __syncthreads();
    const int d = t >> 3, nq = (t & 7) * 4;
    unsigned q0 = (unsigned)f2bf(sT[nq + 0][d]) | ((unsigned)f2bf(sT[nq + 1][d]) << 16);
    unsigned q1 = (unsigned)f2bf(sT[nq + 2][d]) | ((unsigned)f2bf(sT[nq + 3][d]) << 16);
    *(uint2*)(XT + ((size_t)(b * DF + d)) * NT + n0 + nq) = make_uint2(q0, q1);
}

// ---------------------------------------------------------------------------
// main: per block, n-tile of 64 rows x m-slice of 320 rows.
// scores via mfma(A=Xm,B=Xn) -> per-wave row-major S in LDS (b64 writes),
// agg via mfma(A=S,B=H^T) accumulated in regs, atomicAdd to agg buffer.
// ---------------------------------------------------------------------------
__global__ __launch_bounds__(256, 4)
void gsage_main(const unsigned short* __restrict__ Xb,  // [B][NT][32] bf16
                const unsigned short* __restrict__ HT,  // [B][32][NT] bf16
                float* __restrict__ agg)                // [B][NT][32] fp32
{
    __shared__ unsigned short XmL[64 * 40];       // pad 40 (80B rows)
    __shared__ unsigned short HtL[32 * 72];       // pad 72 (144B rows)
    __shared__ unsigned short Ss[4 * 16 * 72];    // per-wave 16n x 64m (pad 72)

    const int t = threadIdx.x;
    const int w = t >> 6, lane = t & 63;
    const int q = lane >> 4, c = lane & 15;
    const int n0 = blockIdx.x * TN;
    const int mbase = blockIdx.y * MROWS;
    const int b = blockIdx.z;

    const size_t xbase = (size_t)b * NT * DF;   // elem offsets (row-major)
    const size_t tbase = (size_t)b * DF * NT;   // elem offsets (transposed)

    // score B-frag: Xn[n = n0+w*16+c][k = q*8 .. q*8+7], constant over m-loop
    const bf16x8 bfn = *(const bf16x8*)(Xb + xbase + (size_t)(n0 + w * 16 + c) * DF + q * 8);

    f32x4 acc0 = {0.f, 0.f, 0.f, 0.f};
    f32x4 acc1 = {0.f, 0.f, 0.f, 0.f};

    const int xrow = t >> 2, xseg = t & 3;   // Xm stage: 64 rows, 4 x 16B
    const int hrow = t >> 3, hseg = t & 7;   // HT stage: 32 rows, 8 x 16B

    uint4 xv = *(const uint4*)(Xb + xbase + (size_t)(mbase + xrow) * DF + xseg * 8);
    uint4 hv = *(const uint4*)(HT + tbase + (size_t)hrow * NT + mbase + hseg * 8);

    const int n_g = n0 + w * 16 + c;
    unsigned short* SsW = Ss + w * (16 * 72);

    for (int it = 0; it < MITERS; ++it) {
        const int m0 = mbase + it * MT;
        __syncthreads();                       // prior iter done reading LDS
        *(uint4*)(XmL + xrow * 40 + xseg * 8) = xv;
        *(uint4*)(HtL + hrow * 72 + hseg * 8) = hv;
        if (it + 1 < MITERS) {
            const int m1 = m0 + MT;
            xv = *(const uint4*)(Xb + xbase + (size_t)(m1 + xrow) * DF + xseg * 8);
            hv = *(const uint4*)(HT + tbase + (size_t)hrow * NT + m1 + hseg * 8);
        }
        __syncthreads();                       // tiles staged

        // ---- scores: St[m][n] tiles; lane holds S[n=c][m = t4*16+q*4+r] ----
        #pragma unroll
        for (int t4 = 0; t4 < 4; ++t4) {
            const bf16x8 af = *(const bf16x8*)(XmL + (t4 * 16 + c) * 40 + q * 8);
            const f32x4 zero = {0.f, 0.f, 0.f, 0.f};
            f32x4 st = __builtin_amdgcn_mfma_f32_16x16x32_bf16(af, bfn, zero, 0, 0, 0);
            const int m2 = m0 + t4 * 16 + q * 4;
            float v0 = tanh_relu(st[0]); if (n_g == m2 + 0) v0 += SELF_EPS;
            float v1 = tanh_relu(st[1]); if (n_g == m2 + 1) v1 += SELF_EPS;
            float v2 = tanh_relu(st[2]); if (n_g == m2 + 2) v2 += SELF_EPS;
            float v3 = tanh_relu(st[3]); if (n_g == m2 + 3) v3 += SELF_EPS;
            unsigned p0 = (unsigned)f2bf(v0) | ((unsigned)f2bf(v1) << 16);
            unsigned p1 = (unsigned)f2bf(v2) | ((unsigned)f2bf(v3) << 16);
            *(uint2*)(SsW + c * 72 + t4 * 16 + q * 4) = make_uint2(p0, p1);
        }
        // cross-lane S visibility within the wave: drain LDS writes
        asm volatile("s_waitcnt lgkmcnt(0)" ::: "memory");

        // ---- agg: acc[n][d] += S[n][m] * H[m][d], K=64 in 2 chunks ----
        #pragma unroll
        for (int kc = 0; kc < 2; ++kc) {
            const bf16x8 sf = *(const bf16x8*)(SsW + c * 72 + kc * 32 + q * 8);
            const bf16x8 h0 = *(const bf16x8*)(HtL + c * 72 + kc * 32 + q * 8);
            const bf16x8 h1 = *(const bf16x8*)(HtL + (16 + c) * 72 + kc * 32 + q * 8);
            acc0 = __builtin_amdgcn_mfma_f32_16x16x32_bf16(sf, h0, acc0, 0, 0, 0);
            acc1 = __builtin_amdgcn_mfma_f32_16x16x32_bf16(sf, h1, acc1, 0, 0, 0);
        }
    }

    // C-layout: row n = n0+w*16+q*4+r, col d = dt*16+c
    float* ap = agg + xbase + (size_t)(n0 + w * 16 + q * 4) * DF + c;
    #pragma unroll
    for (int r = 0; r < 4; ++r) {
        atomicAdd(ap + (size_t)r * DF, acc0[r]);
        atomicAdd(ap + (size_t)r * DF + 16, acc1[r]);
    }
}

// ---------------------------------------------------------------------------
// epilogue: Hout = elu(Hin*Ws + agg*Wn + b); optionally emit Hout^T bf16.
// ---------------------------------------------------------------------------
__global__ __launch_bounds__(256, 4)
void gsage_epi(const float* __restrict__ Hin, const float* __restrict__ agg,
               const float* __restrict__ Wsl, const float* __restrict__ Wnl,
               const float* __restrict__ bl,
               float* __restrict__ Hout, unsigned short* __restrict__ HTout)
{
    __shared__ float sW[32][33], sN[32][33], sH[32][36], sA[32][36], sT[32][33];
    const int t = threadIdx.x;
    const int n0 = blockIdx.x * 32;
    const int b = blockIdx.y;
    const int row = t >> 3, c4 = (t & 7) * 4;
    const size_t rb = ((size_t)(b * NT + n0 + row)) * DF + c4;
    const float4 hv = *(const float4*)(Hin + rb);
    const float4 av = *(const float4*)(agg + rb);
    const float4 w0 = *(const float4*)(Wsl + row * DF + c4);
    const float4 w1 = *(const float4*)(Wnl + row * DF + c4);
    sH[row][c4+0]=hv.x; sH[row][c4+1]=hv.y; sH[row][c4+2]=hv.z; sH[row][c4+3]=hv.w;
    sA[row][c4+0]=av.x; sA[row][c4+1]=av.y; sA[row][c4+2]=av.z; sA[row][c4+3]=av.w;
    sW[row][c4+0]=w0.x; sW[row][c4+1]=w0.y; sW[row][c4+2]=w0.z; sW[row][c4+3]=w0.w;
    sN[row][c4+0]=w1.x; sN[row][c4+1]=w1.y; sN[row][c4+2]=w1.z; sN[row][c4+3]=w1.w;
    __syncthreads();

    float4 z = make_float4(bl[c4+0], bl[c4+1], bl[c4+2], bl[c4+3]);
    #pragma unroll
    for (int k = 0; k < DF; ++k) {
        const float hk = sH[row][k], ak = sA[row][k];
        z.x += hk * sW[k][c4+0] + ak * sN[k][c4+0];
        z.y += hk * sW[k][c4+1] + ak * sN[k][c4+1];
        z.z += hk * sW[k][c4+2] + ak * sN[k][c4+2];
        z.w += hk * sW[k][c4+3] + ak * sN[k][c4+3];
    }
    z.x = z.x > 0.f ? z.x : __expf(z.x) - 1.f;
    z.y = z.y > 0.f ? z.y : __expf(z.y) - 1.f;
    z.z = z.z > 0.f ? z.z : __expf(z.z) - 1.f;
    z.w = z.w > 0.f ? z.w : __expf(z.w) - 1.f;
    *(float4*)(Hout + rb) = z;

    if (HTout != nullptr) {
        sT[row][c4+0]=z.x; sT[row][c4+1]=z.y; sT[row][c4+2]=z.z; sT[row][c4+3]=z.w;
        __syncthreads();
        const int d = t >> 3, nq = (t & 7) * 4;
        unsigned q0 = (unsigned)f2bf(sT[nq+0][d]) | ((unsigned)f2bf(sT[nq+1][d]) << 16);
        unsigned q1 = (unsigned)f2bf(sT[nq+2][d]) | ((unsigned)f2bf(sT[nq+3][d]) << 16);
        *(uint2*)(HTout + ((size_t)(b * DF + d)) * NT + n0 + nq) = make_uint2(q0, q1);
    }
}

extern "C" void kernel_launch(void* const* d_in, const int* in_sizes, int n_in,
                              void* d_out, int out_size, void* d_ws, size_t ws_size,
                              hipStream_t stream) {
    const float* X  = (const float*)d_in[0];
    const float* Ws = (const float*)d_in[1];   // [2][32][32]
    const float* Wn = (const float*)d_in[2];   // [2][32][32]
    const float* bv = (const float*)d_in[3];   // [2][32]
    float* out = (float*)d_out;

    char* ws = (char*)d_ws;
    float* agg1 = (float*)ws;                          // 1,310,720 B
    float* agg2 = agg1 + (size_t)NB * NT * DF;         // 1,310,720 B (contig w/ agg1)
    float* h1   = agg2 + (size_t)NB * NT * DF;         // 1,310,720 B
    unsigned short* Xb  = (unsigned short*)(ws + 3932160);  // 655,360 B
    unsigned short* XT  = Xb + (size_t)NB * NT * DF;        // 655,360 B
    unsigned short* H1T = XT + (size_t)NB * NT * DF;        // 655,360 B

    prep<<<960, 256, 0, stream>>>(X, agg1, Xb, XT);

    dim3 g(NT / TN, MS, NB);   // 40 x 8 x 4 = 1280 blocks
    gsage_main<<<g, 256, 0, stream>>>(Xb, XT, agg1);
    gsage_epi<<<dim3(NT / 32, NB), 256, 0, stream>>>(X, agg1, Ws, Wn, bv, h1, H1T);
    gsage_main<<<g, 256, 0, stream>>>(Xb, H1T, agg2);
    gsage_epi<<<dim3(NT / 32, NB), 256, 0, stream>>>(h1, agg2, Ws + DF * DF, Wn + DF * DF,
                                                     bv + DF, out, nullptr);
}